// Round 10
// baseline (95.992 us; speedup 1.0000x reference)
//
#include <hip/hip_runtime.h>
#include <hip/hip_bf16.h>
#include <stdint.h>

// WindowAttention fused pipeline for MI355X (gfx950).
// f32 I/O, fp16 MFMA compute internally (f32 accum).
// B=8, N=16384, C=128, H=16, ws=128, head-dim D=1024 (buggy-reshape semantics).
//
// Workspace layouts (tile-permuted so phase-1 stores are 512B-contiguous):
//  qk2[b][ft 2048][cb 8][tile 256 u16]  tile = [eg 4][cl 16][4 f]   (f = h*1024+d | +16384 for K)
//  vT2[b][h 16][ddt 64][cb 8][tile 256] tile = [cg 4][ddl 16][4 c']
//  wh [384][128] fp16 (optional, after the two buffers)
//
// r10: T14 async-stage pipelining in both kernels (issue loads early to regs,
// LDS-write late after the hiding compute phase). Layouts identical to r9.

#define B_ 8
#define N_ 16384
#define C_ 128
#define H_ 16
#define E3 384
#define DH 1024

typedef float f32x4 __attribute__((ext_vector_type(4)));
typedef _Float16 f16x8 __attribute__((ext_vector_type(8)));
typedef unsigned short u16x8 __attribute__((ext_vector_type(8)));
typedef unsigned short u16x4 __attribute__((ext_vector_type(4)));

#define MFMA16(a, b, c) __builtin_amdgcn_mfma_f32_16x16x32_f16((a), (b), (c), 0, 0, 0)

__device__ __forceinline__ unsigned short f2h(float f) {
  union { _Float16 h; unsigned short u; } x;
  x.h = (_Float16)f;
  return x.u;
}

// ---------------- Phase 0: W f32 -> f16 ---------------------------------
__global__ __launch_bounds__(256) void convert_w_kernel(const float* __restrict__ wq,
                                                        unsigned short* __restrict__ wh) {
  int i = blockIdx.x * 256 + threadIdx.x;  // 12288 threads x 4 elems
  float4 v = ((const float4*)wq)[i];
  u16x4 o;
  o[0] = f2h(v.x); o[1] = f2h(v.y); o[2] = f2h(v.z); o[3] = f2h(v.w);
  ((u16x4*)wh)[i] = o;
}

// ---------------- Phase 1: QKV projection -------------------------------
// Per (b,w): Out[c][e] = sum_d x[b,w*128+d,c] * W[e][d] + bias[e], f = w*384+e.
// Window-pair pipeline: block = (wp, half, b); windows w0=2wp, w1=2wp+1.
// esub range per block: half*3 .. half*3+2 (W slice shared by both windows).
__global__ __launch_bounds__(256) void qkv_proj_kernel(
    const float* __restrict__ x,
    const float* __restrict__ wq,
    const unsigned short* __restrict__ wh,   // may be null
    const float* __restrict__ bq,
    unsigned short* __restrict__ qk2,
    unsigned short* __restrict__ vT2) {
  const int wp = blockIdx.x & 63;
  const int half = blockIdx.x >> 6;        // esub range: half*3 .. half*3+2
  const int b = blockIdx.y;
  const int t = threadIdx.x;
  const int l = t & 63;
  const int wv = t >> 6;

  __shared__ __align__(16) unsigned short xt[128 * 128];  // swizzled Xt[c][d] (fp16)
  char* xtb = (char*)xt;

  const int w0 = wp * 2, w1 = w0 + 1;
  const float* xg0 = x + ((size_t)(b * N_ + w0 * 128)) * C_;
  const float* xg1 = xg0 + (size_t)128 * C_;

  const int c00 = (wv & 1) * 64;        // wave's c-half
  const int ehalf = (wv >> 1) * 32;     // wave's e-half within 64-wide subtile
  const f32x4 fzero = {0.f, 0.f, 0.f, 0.f};
  const bool useWh = (wh != nullptr);

  f16x8 ax[4][4];

  // Compute the 3 esubs of `half` for window w using current ax registers.
  auto compute_win = [&](int w) {
#pragma unroll
    for (int es = 0; es < 3; ++es) {
      const int esub = half * 3 + es;
      const int e00 = esub * 64 + ehalf;
      const int f00 = w * E3 + e00;
      const int type = f00 >> 14;  // 0,1 -> Q/K ; 2 -> V

      f16x8 bw[2][4];
#pragma unroll
      for (int nf = 0; nf < 2; ++nf)
#pragma unroll
        for (int ks = 0; ks < 4; ++ks) {
          int e = e00 + nf * 16 + (l & 15);
          if (useWh) {
            bw[nf][ks] = *(const f16x8*)(wh + e * 128 + ks * 32 + ((l >> 4) * 8));
          } else {
            const float* wp_ = wq + e * 128 + ks * 32 + ((l >> 4) * 8);
            float4 w0_ = *(const float4*)(wp_);
            float4 w1_ = *(const float4*)(wp_ + 4);
            f16x8 bb;
            bb[0] = (_Float16)w0_.x; bb[1] = (_Float16)w0_.y;
            bb[2] = (_Float16)w0_.z; bb[3] = (_Float16)w0_.w;
            bb[4] = (_Float16)w1_.x; bb[5] = (_Float16)w1_.y;
            bb[6] = (_Float16)w1_.z; bb[7] = (_Float16)w1_.w;
            bw[nf][ks] = bb;
          }
        }

      f32x4 acc[4][2];
#pragma unroll
      for (int mf = 0; mf < 4; ++mf)
#pragma unroll
        for (int nf = 0; nf < 2; ++nf) acc[mf][nf] = fzero;

      if (type < 2) {
        // D[e][c] = mfma(W, X) -> qk2 tile, lane*8B contiguous.
#pragma unroll
        for (int ks = 0; ks < 4; ++ks)
#pragma unroll
          for (int mf = 0; mf < 4; ++mf)
#pragma unroll
            for (int nf = 0; nf < 2; ++nf)
              acc[mf][nf] = MFMA16(bw[nf][ks], ax[mf][ks], acc[mf][nf]);
#pragma unroll
        for (int nf = 0; nf < 2; ++nf) {
          int ft = (f00 + nf * 16) >> 4;
          float4 bb = *(const float4*)(bq + e00 + nf * 16 + ((l >> 4) * 4));
#pragma unroll
          for (int mf = 0; mf < 4; ++mf) {
            int cb = (c00 >> 4) + mf;
            size_t tb = (((size_t)b * 2048 + ft) * 8 + cb) * 256;
            u16x4 ov;
            ov[0] = f2h(acc[mf][nf][0] + bb.x);
            ov[1] = f2h(acc[mf][nf][1] + bb.y);
            ov[2] = f2h(acc[mf][nf][2] + bb.z);
            ov[3] = f2h(acc[mf][nf][3] + bb.w);
            *(u16x4*)(qk2 + tb + l * 4) = ov;
          }
        }
      } else {
        // D[c][e] = mfma(X, W) -> vT2 tile, lane*8B contiguous.
#pragma unroll
        for (int ks = 0; ks < 4; ++ks)
#pragma unroll
          for (int mf = 0; mf < 4; ++mf)
#pragma unroll
            for (int nf = 0; nf < 2; ++nf)
              acc[mf][nf] = MFMA16(ax[mf][ks], bw[nf][ks], acc[mf][nf]);
#pragma unroll
        for (int nf = 0; nf < 2; ++nf) {
          int fnf = f00 + nf * 16;
          int hh = (fnf >> 10) & 15;
          int ddt = (fnf & 1023) >> 4;
          float bias = bq[e00 + nf * 16 + (l & 15)];
#pragma unroll
          for (int mf = 0; mf < 4; ++mf) {
            int cb = (c00 >> 4) + mf;
            size_t tb = ((((size_t)b * 16 + hh) * 64 + ddt) * 8 + cb) * 256;
            u16x4 ov;
#pragma unroll
            for (int r = 0; r < 4; ++r) ov[r] = f2h(acc[mf][nf][r] + bias);
            *(u16x4*)(vT2 + tb + l * 4) = ov;
          }
        }
      }
    }
  };

  // ---- stage w0 directly (load + cvt + swizzled LDS write) ----
#pragma unroll
  for (int it = 0; it < 2; ++it) {
    int task = t + it * 256;
    int c0 = (task & 31) * 4;
    int d0 = (task >> 5) * 8;
    u16x8 pk0, pk1, pk2, pk3;
#pragma unroll
    for (int j = 0; j < 8; ++j) {
      float4 v = *(const float4*)(xg0 + (d0 + j) * C_ + c0);
      pk0[j] = f2h(v.x);
      pk1[j] = f2h(v.y);
      pk2[j] = f2h(v.z);
      pk3[j] = f2h(v.w);
    }
    *(u16x8*)(xtb + c0 * 256 + ((d0 * 2) ^ ((c0 & 7) << 4))) = pk0;
    *(u16x8*)(xtb + (c0 + 1) * 256 + ((d0 * 2) ^ (((c0 + 1) & 7) << 4))) = pk1;
    *(u16x8*)(xtb + (c0 + 2) * 256 + ((d0 * 2) ^ (((c0 + 2) & 7) << 4))) = pk2;
    *(u16x8*)(xtb + (c0 + 3) * 256 + ((d0 * 2) ^ (((c0 + 3) & 7) << 4))) = pk3;
  }
  __syncthreads();  // B1: w0 tile visible

  // hoist ax(w0)
#pragma unroll
  for (int mf = 0; mf < 4; ++mf)
#pragma unroll
    for (int ks = 0; ks < 4; ++ks) {
      int cl = c00 + mf * 16 + (l & 15);
      ax[mf][ks] = *(const f16x8*)(xtb + cl * 256 + (((ks * 64) + ((l >> 4) * 16)) ^ ((cl & 7) << 4)));
    }
  __syncthreads();  // B2: all waves done reading w0 tile; LDS reusable

  // ---- T14: issue w1 stage loads now; they fly during compute_win(w0) ----
  float4 st[16];
#pragma unroll
  for (int it = 0; it < 2; ++it) {
    int task = t + it * 256;
    int c0 = (task & 31) * 4;
    int d0 = (task >> 5) * 8;
#pragma unroll
    for (int j = 0; j < 8; ++j)
      st[it * 8 + j] = *(const float4*)(xg1 + (d0 + j) * C_ + c0);
  }

  compute_win(w0);

  // cvt + LDS-write w1 (compiler inserts counted vmcnt waits here)
#pragma unroll
  for (int it = 0; it < 2; ++it) {
    int task = t + it * 256;
    int c0 = (task & 31) * 4;
    int d0 = (task >> 5) * 8;
    u16x8 pk0, pk1, pk2, pk3;
#pragma unroll
    for (int j = 0; j < 8; ++j) {
      float4 v = st[it * 8 + j];
      pk0[j] = f2h(v.x);
      pk1[j] = f2h(v.y);
      pk2[j] = f2h(v.z);
      pk3[j] = f2h(v.w);
    }
    *(u16x8*)(xtb + c0 * 256 + ((d0 * 2) ^ ((c0 & 7) << 4))) = pk0;
    *(u16x8*)(xtb + (c0 + 1) * 256 + ((d0 * 2) ^ (((c0 + 1) & 7) << 4))) = pk1;
    *(u16x8*)(xtb + (c0 + 2) * 256 + ((d0 * 2) ^ (((c0 + 2) & 7) << 4))) = pk2;
    *(u16x8*)(xtb + (c0 + 3) * 256 + ((d0 * 2) ^ (((c0 + 3) & 7) << 4))) = pk3;
  }
  __syncthreads();  // B3: w1 tile visible

  // hoist ax(w1)
#pragma unroll
  for (int mf = 0; mf < 4; ++mf)
#pragma unroll
    for (int ks = 0; ks < 4; ++ks) {
      int cl = c00 + mf * 16 + (l & 15);
      ax[mf][ks] = *(const f16x8*)(xtb + cl * 256 + (((ks * 64) + ((l >> 4) * 16)) ^ ((cl & 7) << 4)));
    }

  compute_win(w1);
}

// ---------------- Phase 2: attention ------------------------------------
// grid 512 = 4 q-quarters (ch = bid>>7) x 128 (b,h) (bh = bid&127).
// T14: Q/K (and V) tiles for the next chunk are reg-prefetched during MFMA.
__global__ __launch_bounds__(256) void attn_kernel(
    const unsigned short* __restrict__ qk2,
    const unsigned short* __restrict__ vT2,
    float* __restrict__ out) {
  const int bid = blockIdx.x;
  const int ch = bid >> 7;               // q-row quarter [0,4)
  const int bh = bid & 127;              // (b,h) [0,128)
  const int b = bh >> 4;
  const int h = bh & 15;
  const int t = threadIdx.x;
  const int l = t & 63;
  const int wv = t >> 6;

  __shared__ __align__(16) char smem[8192 + 32768 + 2048];
  char* QS = smem;                        // Q tiles (32 rows x 256B), later P
  char* KS = smem + 8192;                 // K tiles / V tiles (128 rows x 256B)
  float* RED = (float*)(smem + 40960);    // [32][4] max ; +256 floats: [32][4] sum

  const f32x4 fzero = {0.f, 0.f, 0.f, 0.f};
  f32x4 acc[2][2];
#pragma unroll
  for (int mf = 0; mf < 2; ++mf)
#pragma unroll
    for (int nf = 0; nf < 2; ++nf) acc[mf][nf] = fzero;

  const int e0w = wv * 32;

  // ---- S = Q K^T over d=1024 in 8 chunks of 128, reg-prefetched ----
  uint4 qv[2], kv[8];
  {
    const int ft0q = h * 64;
    const int ft0k = 1024 + h * 64;
#pragma unroll
    for (int i = 0; i < 2; ++i) {
      int idx = t + i * 256;
      int ftl = idx >> 6, cbl = (idx >> 5) & 1, m = idx & 31;
      qv[i] = *(const uint4*)(qk2 + (((size_t)b * 2048 + ft0q + ftl) * 8 + ch * 2 + cbl) * 256 + m * 8);
    }
#pragma unroll
    for (int i = 0; i < 8; ++i) {
      int idx = t + i * 256;
      int ftl = idx >> 8, cb = (idx >> 5) & 7, m = idx & 31;
      kv[i] = *(const uint4*)(qk2 + (((size_t)b * 2048 + ft0k + ftl) * 8 + cb) * 256 + m * 8);
    }
  }

  for (int dc = 0; dc < 8; ++dc) {
    if (dc) __syncthreads();  // prev MFMA done reading LDS
    // LDS writes from staged regs
#pragma unroll
    for (int i = 0; i < 2; ++i) {
      int idx = t + i * 256;
      int ftl = idx >> 6, cbl = (idx >> 5) & 1, m = idx & 31;
      int row0 = cbl * 16 + (m & 7) * 2;
      int fb = ftl * 32 + (m >> 3) * 8;
      uint4 v = qv[i];
      *(uint2*)(QS + row0 * 256 + (fb ^ ((row0 & 7) << 4))) = make_uint2(v.x, v.y);
      *(uint2*)(QS + (row0 + 1) * 256 + (fb ^ (((row0 + 1) & 7) << 4))) = make_uint2(v.z, v.w);
    }
#pragma unroll
    for (int i = 0; i < 8; ++i) {
      int idx = t + i * 256;
      int ftl = idx >> 8, cb = (idx >> 5) & 7, m = idx & 31;
      int row0 = cb * 16 + (m & 7) * 2;
      int fb = ftl * 32 + (m >> 3) * 8;
      uint4 v = kv[i];
      *(uint2*)(KS + row0 * 256 + (fb ^ ((row0 & 7) << 4))) = make_uint2(v.x, v.y);
      *(uint2*)(KS + (row0 + 1) * 256 + (fb ^ (((row0 + 1) & 7) << 4))) = make_uint2(v.z, v.w);
    }
    __syncthreads();  // tiles visible

    if (dc < 7) {  // prefetch next chunk; lands during MFMA below
      const int ft0q = h * 64 + (dc + 1) * 8;
      const int ft0k = 1024 + h * 64 + (dc + 1) * 8;
#pragma unroll
      for (int i = 0; i < 2; ++i) {
        int idx = t + i * 256;
        int ftl = idx >> 6, cbl = (idx >> 5) & 1, m = idx & 31;
        qv[i] = *(const uint4*)(qk2 + (((size_t)b * 2048 + ft0q + ftl) * 8 + ch * 2 + cbl) * 256 + m * 8);
      }
#pragma unroll
      for (int i = 0; i < 8; ++i) {
        int idx = t + i * 256;
        int ftl = idx >> 8, cb = (idx >> 5) & 7, m = idx & 31;
        kv[i] = *(const uint4*)(qk2 + (((size_t)b * 2048 + ft0k + ftl) * 8 + cb) * 256 + m * 8);
      }
    }

#pragma unroll
    for (int ks = 0; ks < 4; ++ks) {
      f16x8 aQ[2], bK[2];
#pragma unroll
      for (int mf = 0; mf < 2; ++mf) {
        int cl = mf * 16 + (l & 15);
        aQ[mf] = *(const f16x8*)(QS + cl * 256 + (((ks * 64) + ((l >> 4) * 16)) ^ ((cl & 7) << 4)));
      }
#pragma unroll
      for (int nf = 0; nf < 2; ++nf) {
        int el = e0w + nf * 16 + (l & 15);
        bK[nf] = *(const f16x8*)(KS + el * 256 + (((ks * 64) + ((l >> 4) * 16)) ^ ((el & 7) << 4)));
      }
#pragma unroll
      for (int mf = 0; mf < 2; ++mf)
#pragma unroll
        for (int nf = 0; nf < 2; ++nf)
          acc[mf][nf] = MFMA16(aQ[mf], bK[nf], acc[mf][nf]);  // D[c][e]
    }
  }

  // ---- V(dc2=0) prefetch: hides under softmax ----
  uint4 vv[8];
#pragma unroll
  for (int i = 0; i < 8; ++i) {
    int idx = t + i * 256;
    int ddtl = idx >> 8, cb = (idx >> 5) & 7, m = idx & 31;
    vv[i] = *(const uint4*)(vT2 + ((((size_t)(b * 16 + h)) * 64 + ddtl) * 8 + cb) * 256 + m * 8);
  }

  // ---- softmax over e (rows c rel), cross-wave combine via RED ----
  const float SC = 0.35355339059327f * 1.44269504088896f;  // 8^-0.5 * log2(e)
  float mrow[2][4];
#pragma unroll
  for (int mf = 0; mf < 2; ++mf)
#pragma unroll
    for (int r = 0; r < 4; ++r) {
      float mx = fmaxf(acc[mf][0][r], acc[mf][1][r]);
      mx = fmaxf(mx, __shfl_xor(mx, 1));
      mx = fmaxf(mx, __shfl_xor(mx, 2));
      mx = fmaxf(mx, __shfl_xor(mx, 4));
      mx = fmaxf(mx, __shfl_xor(mx, 8));
      int cl = mf * 16 + ((l >> 4) * 4) + r;
      if ((l & 15) == 0) RED[cl * 4 + wv] = mx;
    }
  __syncthreads();
#pragma unroll
  for (int mf = 0; mf < 2; ++mf)
#pragma unroll
    for (int r = 0; r < 4; ++r) {
      int cl = mf * 16 + ((l >> 4) * 4) + r;
      float4 v = *(const float4*)(RED + cl * 4);
      mrow[mf][r] = fmaxf(fmaxf(v.x, v.y), fmaxf(v.z, v.w));
    }
#pragma unroll
  for (int mf = 0; mf < 2; ++mf)
#pragma unroll
    for (int r = 0; r < 4; ++r) {
      float s0 = 0.f;
#pragma unroll
      for (int nf = 0; nf < 2; ++nf) {
        float p = exp2f((acc[mf][nf][r] - mrow[mf][r]) * SC);
        acc[mf][nf][r] = p;
        s0 += p;
      }
      s0 += __shfl_xor(s0, 1);
      s0 += __shfl_xor(s0, 2);
      s0 += __shfl_xor(s0, 4);
      s0 += __shfl_xor(s0, 8);
      int cl = mf * 16 + ((l >> 4) * 4) + r;
      if ((l & 15) == 0) RED[256 + cl * 4 + wv] = s0;
    }
  // write P (fp16) into QS
#pragma unroll
  for (int mf = 0; mf < 2; ++mf)
#pragma unroll
    for (int nf = 0; nf < 2; ++nf)
#pragma unroll
      for (int r = 0; r < 4; ++r) {
        int cl = mf * 16 + ((l >> 4) * 4) + r;
        int el = e0w + nf * 16 + (l & 15);
        *(unsigned short*)(QS + cl * 256 + ((el * 2) ^ ((cl & 7) << 4))) = f2h(acc[mf][nf][r]);
      }
  __syncthreads();
  float invc[2];
#pragma unroll
  for (int mf = 0; mf < 2; ++mf) {
    int cl = mf * 16 + (l & 15);
    float4 v = *(const float4*)(RED + 256 + cl * 4);
    invc[mf] = 1.f / (v.x + v.y + v.z + v.w);
  }

  // ---- O = P V; D[d][c] via mfma(V,P); V tiles reg-prefetched ----
  for (int dc2 = 0; dc2 < 8; ++dc2) {
    if (dc2) __syncthreads();  // prev MFMA done reading KS
    // write KS (V^T chunk) from staged regs
#pragma unroll
    for (int i = 0; i < 8; ++i) {
      int idx = t + i * 256;
      int ddtl = idx >> 8, cb = (idx >> 5) & 7, m = idx & 31;
      int row0 = ddtl * 16 + (m & 7) * 2;
      int cbyte = cb * 32 + (m >> 3) * 8;
      uint4 v = vv[i];
      *(uint2*)(KS + row0 * 256 + (cbyte ^ ((row0 & 7) << 4))) = make_uint2(v.x, v.y);
      *(uint2*)(KS + (row0 + 1) * 256 + (cbyte ^ (((row0 + 1) & 7) << 4))) = make_uint2(v.z, v.w);
    }
    __syncthreads();

    if (dc2 < 7) {  // prefetch next V chunk
#pragma unroll
      for (int i = 0; i < 8; ++i) {
        int idx = t + i * 256;
        int ddtl = idx >> 8, cb = (idx >> 5) & 7, m = idx & 31;
        vv[i] = *(const uint4*)(vT2 + ((((size_t)(b * 16 + h)) * 64 + (dc2 + 1) * 8 + ddtl) * 8 + cb) * 256 + m * 8);
      }
    }

    f32x4 acc2[2][2];  // [nf: d-tile][mf: c-tile]
#pragma unroll
    for (int nf = 0; nf < 2; ++nf)
#pragma unroll
      for (int mf = 0; mf < 2; ++mf) acc2[nf][mf] = fzero;

#pragma unroll
    for (int ks = 0; ks < 4; ++ks) {
      f16x8 aP[2], bV[2];
#pragma unroll
      for (int mf = 0; mf < 2; ++mf) {
        int cl = mf * 16 + (l & 15);
        aP[mf] = *(const f16x8*)(QS + cl * 256 + (((ks * 64) + ((l >> 4) * 16)) ^ ((cl & 7) << 4)));
      }
#pragma unroll
      for (int nf = 0; nf < 2; ++nf) {
        int dl = e0w + nf * 16 + (l & 15);
        bV[nf] = *(const f16x8*)(KS + dl * 256 + (((ks * 64) + ((l >> 4) * 16)) ^ ((dl & 7) << 4)));
      }
#pragma unroll
      for (int nf = 0; nf < 2; ++nf)
#pragma unroll
        for (int mf = 0; mf < 2; ++mf)
          acc2[nf][mf] = MFMA16(bV[nf], aP[mf], acc2[nf][mf]);  // D[d][c]
    }

#pragma unroll
    for (int nf = 0; nf < 2; ++nf)
#pragma unroll
      for (int mf = 0; mf < 2; ++mf) {
        int c = ch * 32 + mf * 16 + (l & 15);
#pragma unroll
        for (int r = 0; r < 4; ++r) {
          int d = dc2 * 128 + e0w + nf * 16 + ((l >> 4) * 4) + r;
          out[((size_t)(b * N_ + h * DH + d)) * C_ + c] = acc2[nf][mf][r] * invc[mf];
        }
      }
  }
}

extern "C" void kernel_launch(void* const* d_in, const int* in_sizes, int n_in,
                              void* d_out, int out_size, void* d_ws, size_t ws_size,
                              hipStream_t stream) {
  const float* x = (const float*)d_in[0];
  const float* wq = (const float*)d_in[1];
  const float* bq = (const float*)d_in[2];
  unsigned short* qk2 = (unsigned short*)d_ws;              // 33,554,432 u16
  unsigned short* vT2 = qk2 + 33554432UL;                   // 16,777,216 u16
  unsigned short* wh = vT2 + 16777216UL;                    // 49,152 u16 (optional)

  const size_t baseNeed = (33554432UL + 16777216UL) * 2;
  if (ws_size < baseNeed) return;
  const bool useWh = ws_size >= baseNeed + 49152UL * 2;

  if (useWh) convert_w_kernel<<<48, 256, 0, stream>>>(wq, wh);
  qkv_proj_kernel<<<dim3(128, 8), 256, 0, stream>>>(x, wq, useWh ? wh : nullptr, bq, qk2, vT2);
  attn_kernel<<<512, 256, 0, stream>>>(qk2, vT2, (float*)d_out);
}

// Round 11
// 90.659 us; speedup vs baseline: 1.0588x; 1.0588x over previous
//
#include <hip/hip_runtime.h>
#include <hip/hip_bf16.h>
#include <stdint.h>

// WindowAttention fused pipeline for MI355X (gfx950).
// f32 I/O, fp16 MFMA compute internally (f32 accum).
// B=8, N=16384, C=128, H=16, ws=128, head-dim D=1024 (buggy-reshape semantics).
//
// Workspace layouts (tile-permuted so phase-1 stores are 512B-contiguous):
//  qk2[b][ft 2048][cb 8][tile 256 u16]  tile = [eg 4][cl 16][4 f]   (f = h*1024+d | +16384 for K)
//  vT2[b][h 16][ddt 64][cb 8][tile 256] tile = [cg 4][ddl 16][4 c']
//  wh [384][128] fp16 (optional, after the two buffers)
//
// r11: qkv = r9 geometry (best: 55us) + NON-TEMPORAL workspace stores (written
// once, consumed by another kernel on another XCD -> don't retain in L2).
// attn = r10 reg-prefetch version (measured ~25us vs r9's ~30us).

#define B_ 8
#define N_ 16384
#define C_ 128
#define H_ 16
#define E3 384
#define DH 1024

typedef float f32x4 __attribute__((ext_vector_type(4)));
typedef _Float16 f16x8 __attribute__((ext_vector_type(8)));
typedef unsigned short u16x8 __attribute__((ext_vector_type(8)));
typedef unsigned short u16x4 __attribute__((ext_vector_type(4)));

#define MFMA16(a, b, c) __builtin_amdgcn_mfma_f32_16x16x32_f16((a), (b), (c), 0, 0, 0)

__device__ __forceinline__ unsigned short f2h(float f) {
  union { _Float16 h; unsigned short u; } x;
  x.h = (_Float16)f;
  return x.u;
}

__device__ __forceinline__ void nt_store8(unsigned short* p, u16x4 v) {
  union { u16x4 v; unsigned long long u; } cv;
  cv.v = v;
  __builtin_nontemporal_store(cv.u, (unsigned long long*)p);
}

// ---------------- Phase 0: W f32 -> f16 ---------------------------------
__global__ __launch_bounds__(256) void convert_w_kernel(const float* __restrict__ wq,
                                                        unsigned short* __restrict__ wh) {
  int i = blockIdx.x * 256 + threadIdx.x;  // 12288 threads x 4 elems
  float4 v = ((const float4*)wq)[i];
  u16x4 o;
  o[0] = f2h(v.x); o[1] = f2h(v.y); o[2] = f2h(v.z); o[3] = f2h(v.w);
  ((u16x4*)wh)[i] = o;
}

// ---------------- Phase 1: QKV projection -------------------------------
// Per (b,w): Out[c][e] = sum_d x[b,w*128+d,c] * W[e][d] + bias[e], f = w*384+e.
// esub-split (r9): blockIdx.x = (half<<7) | w; each block stages the full
// x-tile, computes 3 of 6 esub subtiles. Grid 2048 x 8.
__global__ __launch_bounds__(256) void qkv_proj_kernel(
    const float* __restrict__ x,
    const float* __restrict__ wq,
    const unsigned short* __restrict__ wh,   // may be null
    const float* __restrict__ bq,
    unsigned short* __restrict__ qk2,
    unsigned short* __restrict__ vT2) {
  const int w = blockIdx.x & 127;
  const int half = blockIdx.x >> 7;        // esub range: half*3 .. half*3+2
  const int b = blockIdx.y;
  const int t = threadIdx.x;
  const int l = t & 63;
  const int wv = t >> 6;

  __shared__ __align__(16) unsigned short xt[128 * 128];  // swizzled Xt[c][d] (fp16)
  char* xtb = (char*)xt;

  const float* xg = x + ((size_t)(b * N_ + w * 128)) * C_;
  // Transpose-stage: float4 loads (4 consecutive c per lane), packed b128
  // swizzled LDS writes. 512 tasks = 32 c-quads x 16 d-groups.
#pragma unroll
  for (int it = 0; it < 2; ++it) {
    int task = t + it * 256;
    int c0 = (task & 31) * 4;
    int d0 = (task >> 5) * 8;
    u16x8 pk0, pk1, pk2, pk3;
#pragma unroll
    for (int j = 0; j < 8; ++j) {
      float4 v = *(const float4*)(xg + (d0 + j) * C_ + c0);
      pk0[j] = f2h(v.x);
      pk1[j] = f2h(v.y);
      pk2[j] = f2h(v.z);
      pk3[j] = f2h(v.w);
    }
    *(u16x8*)(xtb + c0 * 256 + ((d0 * 2) ^ ((c0 & 7) << 4))) = pk0;
    *(u16x8*)(xtb + (c0 + 1) * 256 + ((d0 * 2) ^ (((c0 + 1) & 7) << 4))) = pk1;
    *(u16x8*)(xtb + (c0 + 2) * 256 + ((d0 * 2) ^ (((c0 + 2) & 7) << 4))) = pk2;
    *(u16x8*)(xtb + (c0 + 3) * 256 + ((d0 * 2) ^ (((c0 + 3) & 7) << 4))) = pk3;
  }
  __syncthreads();

  const int c00 = (wv & 1) * 64;        // wave's c-half
  const int ehalf = (wv >> 1) * 32;     // wave's e-half within 64-wide subtile

  // Hoist X fragments: a(c,d), reused across the block's 3 e-subtiles.
  f16x8 ax[4][4];
#pragma unroll
  for (int mf = 0; mf < 4; ++mf)
#pragma unroll
    for (int ks = 0; ks < 4; ++ks) {
      int cl = c00 + mf * 16 + (l & 15);
      ax[mf][ks] = *(const f16x8*)(xtb + cl * 256 + (((ks * 64) + ((l >> 4) * 16)) ^ ((cl & 7) << 4)));
    }

  const f32x4 fzero = {0.f, 0.f, 0.f, 0.f};
  const bool useWh = (wh != nullptr);

#pragma unroll
  for (int es = 0; es < 3; ++es) {
    const int esub = half * 3 + es;
    const int e00 = esub * 64 + ehalf;
    const int f00 = w * E3 + e00;
    const int type = f00 >> 14;  // 0,1 -> Q/K ; 2 -> V (uniform per 32-wide tile)

    f16x8 bw[2][4];
#pragma unroll
    for (int nf = 0; nf < 2; ++nf)
#pragma unroll
      for (int ks = 0; ks < 4; ++ks) {
        int e = e00 + nf * 16 + (l & 15);
        if (useWh) {
          bw[nf][ks] = *(const f16x8*)(wh + e * 128 + ks * 32 + ((l >> 4) * 8));
        } else {
          const float* wp = wq + e * 128 + ks * 32 + ((l >> 4) * 8);
          float4 w0 = *(const float4*)(wp);
          float4 w1 = *(const float4*)(wp + 4);
          f16x8 bb;
          bb[0] = (_Float16)w0.x; bb[1] = (_Float16)w0.y;
          bb[2] = (_Float16)w0.z; bb[3] = (_Float16)w0.w;
          bb[4] = (_Float16)w1.x; bb[5] = (_Float16)w1.y;
          bb[6] = (_Float16)w1.z; bb[7] = (_Float16)w1.w;
          bw[nf][ks] = bb;
        }
      }

    f32x4 acc[4][2];
#pragma unroll
    for (int mf = 0; mf < 4; ++mf)
#pragma unroll
      for (int nf = 0; nf < 2; ++nf) acc[mf][nf] = fzero;

    if (type < 2) {
      // D[e][c] = mfma(W, X): tile [eg=l>>4][cl=l&15][4 e] -> lane*8B contiguous.
#pragma unroll
      for (int ks = 0; ks < 4; ++ks)
#pragma unroll
        for (int mf = 0; mf < 4; ++mf)
#pragma unroll
          for (int nf = 0; nf < 2; ++nf)
            acc[mf][nf] = MFMA16(bw[nf][ks], ax[mf][ks], acc[mf][nf]);
#pragma unroll
      for (int nf = 0; nf < 2; ++nf) {
        int ft = (f00 + nf * 16) >> 4;
        float4 bb = *(const float4*)(bq + e00 + nf * 16 + ((l >> 4) * 4));
#pragma unroll
        for (int mf = 0; mf < 4; ++mf) {
          int cb = (c00 >> 4) + mf;
          size_t tb = (((size_t)b * 2048 + ft) * 8 + cb) * 256;
          u16x4 ov;
          ov[0] = f2h(acc[mf][nf][0] + bb.x);
          ov[1] = f2h(acc[mf][nf][1] + bb.y);
          ov[2] = f2h(acc[mf][nf][2] + bb.z);
          ov[3] = f2h(acc[mf][nf][3] + bb.w);
          nt_store8(qk2 + tb + l * 4, ov);
        }
      }
    } else {
      // D[c][e] = mfma(X, W): tile [cg=l>>4][ddl=l&15][4 c] -> lane*8B contiguous.
#pragma unroll
      for (int ks = 0; ks < 4; ++ks)
#pragma unroll
        for (int mf = 0; mf < 4; ++mf)
#pragma unroll
          for (int nf = 0; nf < 2; ++nf)
            acc[mf][nf] = MFMA16(ax[mf][ks], bw[nf][ks], acc[mf][nf]);
#pragma unroll
      for (int nf = 0; nf < 2; ++nf) {
        int fnf = f00 + nf * 16;
        int hh = (fnf >> 10) & 15;
        int ddt = (fnf & 1023) >> 4;
        float bias = bq[e00 + nf * 16 + (l & 15)];  // bias for this lane's e-column
#pragma unroll
        for (int mf = 0; mf < 4; ++mf) {
          int cb = (c00 >> 4) + mf;
          size_t tb = ((((size_t)b * 16 + hh) * 64 + ddt) * 8 + cb) * 256;
          u16x4 ov;
#pragma unroll
          for (int r = 0; r < 4; ++r) ov[r] = f2h(acc[mf][nf][r] + bias);
          nt_store8(vT2 + tb + l * 4, ov);
        }
      }
    }
  }
}

// ---------------- Phase 2: attention ------------------------------------
// grid 512 = 4 q-quarters (ch = bid>>7) x 128 (b,h) (bh = bid&127).
// T14: Q/K (and V) tiles for the next chunk are reg-prefetched during MFMA.
__global__ __launch_bounds__(256) void attn_kernel(
    const unsigned short* __restrict__ qk2,
    const unsigned short* __restrict__ vT2,
    float* __restrict__ out) {
  const int bid = blockIdx.x;
  const int ch = bid >> 7;               // q-row quarter [0,4)
  const int bh = bid & 127;              // (b,h) [0,128)
  const int b = bh >> 4;
  const int h = bh & 15;
  const int t = threadIdx.x;
  const int l = t & 63;
  const int wv = t >> 6;

  __shared__ __align__(16) char smem[8192 + 32768 + 2048];
  char* QS = smem;                        // Q tiles (32 rows x 256B), later P
  char* KS = smem + 8192;                 // K tiles / V tiles (128 rows x 256B)
  float* RED = (float*)(smem + 40960);    // [32][4] max ; +256 floats: [32][4] sum

  const f32x4 fzero = {0.f, 0.f, 0.f, 0.f};
  f32x4 acc[2][2];
#pragma unroll
  for (int mf = 0; mf < 2; ++mf)
#pragma unroll
    for (int nf = 0; nf < 2; ++nf) acc[mf][nf] = fzero;

  const int e0w = wv * 32;

  // ---- S = Q K^T over d=1024 in 8 chunks of 128, reg-prefetched ----
  uint4 qv[2], kv[8];
  {
    const int ft0q = h * 64;
    const int ft0k = 1024 + h * 64;
#pragma unroll
    for (int i = 0; i < 2; ++i) {
      int idx = t + i * 256;
      int ftl = idx >> 6, cbl = (idx >> 5) & 1, m = idx & 31;
      qv[i] = *(const uint4*)(qk2 + (((size_t)b * 2048 + ft0q + ftl) * 8 + ch * 2 + cbl) * 256 + m * 8);
    }
#pragma unroll
    for (int i = 0; i < 8; ++i) {
      int idx = t + i * 256;
      int ftl = idx >> 8, cb = (idx >> 5) & 7, m = idx & 31;
      kv[i] = *(const uint4*)(qk2 + (((size_t)b * 2048 + ft0k + ftl) * 8 + cb) * 256 + m * 8);
    }
  }

  for (int dc = 0; dc < 8; ++dc) {
    if (dc) __syncthreads();  // prev MFMA done reading LDS
    // LDS writes from staged regs
#pragma unroll
    for (int i = 0; i < 2; ++i) {
      int idx = t + i * 256;
      int ftl = idx >> 6, cbl = (idx >> 5) & 1, m = idx & 31;
      int row0 = cbl * 16 + (m & 7) * 2;
      int fb = ftl * 32 + (m >> 3) * 8;
      uint4 v = qv[i];
      *(uint2*)(QS + row0 * 256 + (fb ^ ((row0 & 7) << 4))) = make_uint2(v.x, v.y);
      *(uint2*)(QS + (row0 + 1) * 256 + (fb ^ (((row0 + 1) & 7) << 4))) = make_uint2(v.z, v.w);
    }
#pragma unroll
    for (int i = 0; i < 8; ++i) {
      int idx = t + i * 256;
      int ftl = idx >> 8, cb = (idx >> 5) & 7, m = idx & 31;
      int row0 = cb * 16 + (m & 7) * 2;
      int fb = ftl * 32 + (m >> 3) * 8;
      uint4 v = kv[i];
      *(uint2*)(KS + row0 * 256 + (fb ^ ((row0 & 7) << 4))) = make_uint2(v.x, v.y);
      *(uint2*)(KS + (row0 + 1) * 256 + (fb ^ (((row0 + 1) & 7) << 4))) = make_uint2(v.z, v.w);
    }
    __syncthreads();  // tiles visible

    if (dc < 7) {  // prefetch next chunk; lands during MFMA below
      const int ft0q = h * 64 + (dc + 1) * 8;
      const int ft0k = 1024 + h * 64 + (dc + 1) * 8;
#pragma unroll
      for (int i = 0; i < 2; ++i) {
        int idx = t + i * 256;
        int ftl = idx >> 6, cbl = (idx >> 5) & 1, m = idx & 31;
        qv[i] = *(const uint4*)(qk2 + (((size_t)b * 2048 + ft0q + ftl) * 8 + ch * 2 + cbl) * 256 + m * 8);
      }
#pragma unroll
      for (int i = 0; i < 8; ++i) {
        int idx = t + i * 256;
        int ftl = idx >> 8, cb = (idx >> 5) & 7, m = idx & 31;
        kv[i] = *(const uint4*)(qk2 + (((size_t)b * 2048 + ft0k + ftl) * 8 + cb) * 256 + m * 8);
      }
    }

#pragma unroll
    for (int ks = 0; ks < 4; ++ks) {
      f16x8 aQ[2], bK[2];
#pragma unroll
      for (int mf = 0; mf < 2; ++mf) {
        int cl = mf * 16 + (l & 15);
        aQ[mf] = *(const f16x8*)(QS + cl * 256 + (((ks * 64) + ((l >> 4) * 16)) ^ ((cl & 7) << 4)));
      }
#pragma unroll
      for (int nf = 0; nf < 2; ++nf) {
        int el = e0w + nf * 16 + (l & 15);
        bK[nf] = *(const f16x8*)(KS + el * 256 + (((ks * 64) + ((l >> 4) * 16)) ^ ((el & 7) << 4)));
      }
#pragma unroll
      for (int mf = 0; mf < 2; ++mf)
#pragma unroll
        for (int nf = 0; nf < 2; ++nf)
          acc[mf][nf] = MFMA16(aQ[mf], bK[nf], acc[mf][nf]);  // D[c][e]
    }
  }

  // ---- V(dc2=0) prefetch: hides under softmax ----
  uint4 vv[8];
#pragma unroll
  for (int i = 0; i < 8; ++i) {
    int idx = t + i * 256;
    int ddtl = idx >> 8, cb = (idx >> 5) & 7, m = idx & 31;
    vv[i] = *(const uint4*)(vT2 + ((((size_t)(b * 16 + h)) * 64 + ddtl) * 8 + cb) * 256 + m * 8);
  }

  // ---- softmax over e (rows c rel), cross-wave combine via RED ----
  const float SC = 0.35355339059327f * 1.44269504088896f;  // 8^-0.5 * log2(e)
  float mrow[2][4];
#pragma unroll
  for (int mf = 0; mf < 2; ++mf)
#pragma unroll
    for (int r = 0; r < 4; ++r) {
      float mx = fmaxf(acc[mf][0][r], acc[mf][1][r]);
      mx = fmaxf(mx, __shfl_xor(mx, 1));
      mx = fmaxf(mx, __shfl_xor(mx, 2));
      mx = fmaxf(mx, __shfl_xor(mx, 4));
      mx = fmaxf(mx, __shfl_xor(mx, 8));
      int cl = mf * 16 + ((l >> 4) * 4) + r;
      if ((l & 15) == 0) RED[cl * 4 + wv] = mx;
    }
  __syncthreads();
#pragma unroll
  for (int mf = 0; mf < 2; ++mf)
#pragma unroll
    for (int r = 0; r < 4; ++r) {
      int cl = mf * 16 + ((l >> 4) * 4) + r;
      float4 v = *(const float4*)(RED + cl * 4);
      mrow[mf][r] = fmaxf(fmaxf(v.x, v.y), fmaxf(v.z, v.w));
    }
#pragma unroll
  for (int mf = 0; mf < 2; ++mf)
#pragma unroll
    for (int r = 0; r < 4; ++r) {
      float s0 = 0.f;
#pragma unroll
      for (int nf = 0; nf < 2; ++nf) {
        float p = exp2f((acc[mf][nf][r] - mrow[mf][r]) * SC);
        acc[mf][nf][r] = p;
        s0 += p;
      }
      s0 += __shfl_xor(s0, 1);
      s0 += __shfl_xor(s0, 2);
      s0 += __shfl_xor(s0, 4);
      s0 += __shfl_xor(s0, 8);
      int cl = mf * 16 + ((l >> 4) * 4) + r;
      if ((l & 15) == 0) RED[256 + cl * 4 + wv] = s0;
    }
  // write P (fp16) into QS
#pragma unroll
  for (int mf = 0; mf < 2; ++mf)
#pragma unroll
    for (int nf = 0; nf < 2; ++nf)
#pragma unroll
      for (int r = 0; r < 4; ++r) {
        int cl = mf * 16 + ((l >> 4) * 4) + r;
        int el = e0w + nf * 16 + (l & 15);
        *(unsigned short*)(QS + cl * 256 + ((el * 2) ^ ((cl & 7) << 4))) = f2h(acc[mf][nf][r]);
      }
  __syncthreads();
  float invc[2];
#pragma unroll
  for (int mf = 0; mf < 2; ++mf) {
    int cl = mf * 16 + (l & 15);
    float4 v = *(const float4*)(RED + 256 + cl * 4);
    invc[mf] = 1.f / (v.x + v.y + v.z + v.w);
  }

  // ---- O = P V; D[d][c] via mfma(V,P); V tiles reg-prefetched ----
  for (int dc2 = 0; dc2 < 8; ++dc2) {
    if (dc2) __syncthreads();  // prev MFMA done reading KS
    // write KS (V^T chunk) from staged regs
#pragma unroll
    for (int i = 0; i < 8; ++i) {
      int idx = t + i * 256;
      int ddtl = idx >> 8, cb = (idx >> 5) & 7, m = idx & 31;
      int row0 = ddtl * 16 + (m & 7) * 2;
      int cbyte = cb * 32 + (m >> 3) * 8;
      uint4 v = vv[i];
      *(uint2*)(KS + row0 * 256 + (cbyte ^ ((row0 & 7) << 4))) = make_uint2(v.x, v.y);
      *(uint2*)(KS + (row0 + 1) * 256 + (cbyte ^ (((row0 + 1) & 7) << 4))) = make_uint2(v.z, v.w);
    }
    __syncthreads();

    if (dc2 < 7) {  // prefetch next V chunk
#pragma unroll
      for (int i = 0; i < 8; ++i) {
        int idx = t + i * 256;
        int ddtl = idx >> 8, cb = (idx >> 5) & 7, m = idx & 31;
        vv[i] = *(const uint4*)(vT2 + ((((size_t)(b * 16 + h)) * 64 + (dc2 + 1) * 8 + ddtl) * 8 + cb) * 256 + m * 8);
      }
    }

    f32x4 acc2[2][2];  // [nf: d-tile][mf: c-tile]
#pragma unroll
    for (int nf = 0; nf < 2; ++nf)
#pragma unroll
      for (int mf = 0; mf < 2; ++mf) acc2[nf][mf] = fzero;

#pragma unroll
    for (int ks = 0; ks < 4; ++ks) {
      f16x8 aP[2], bV[2];
#pragma unroll
      for (int mf = 0; mf < 2; ++mf) {
        int cl = mf * 16 + (l & 15);
        aP[mf] = *(const f16x8*)(QS + cl * 256 + (((ks * 64) + ((l >> 4) * 16)) ^ ((cl & 7) << 4)));
      }
#pragma unroll
      for (int nf = 0; nf < 2; ++nf) {
        int dl = e0w + nf * 16 + (l & 15);
        bV[nf] = *(const f16x8*)(KS + dl * 256 + (((ks * 64) + ((l >> 4) * 16)) ^ ((dl & 7) << 4)));
      }
#pragma unroll
      for (int nf = 0; nf < 2; ++nf)
#pragma unroll
        for (int mf = 0; mf < 2; ++mf)
          acc2[nf][mf] = MFMA16(bV[nf], aP[mf], acc2[nf][mf]);  // D[d][c]
    }

#pragma unroll
    for (int nf = 0; nf < 2; ++nf)
#pragma unroll
      for (int mf = 0; mf < 2; ++mf) {
        int c = ch * 32 + mf * 16 + (l & 15);
#pragma unroll
        for (int r = 0; r < 4; ++r) {
          int d = dc2 * 128 + e0w + nf * 16 + ((l >> 4) * 4) + r;
          out[((size_t)(b * N_ + h * DH + d)) * C_ + c] = acc2[nf][mf][r] * invc[mf];
        }
      }
  }
}

extern "C" void kernel_launch(void* const* d_in, const int* in_sizes, int n_in,
                              void* d_out, int out_size, void* d_ws, size_t ws_size,
                              hipStream_t stream) {
  const float* x = (const float*)d_in[0];
  const float* wq = (const float*)d_in[1];
  const float* bq = (const float*)d_in[2];
  unsigned short* qk2 = (unsigned short*)d_ws;              // 33,554,432 u16
  unsigned short* vT2 = qk2 + 33554432UL;                   // 16,777,216 u16
  unsigned short* wh = vT2 + 16777216UL;                    // 49,152 u16 (optional)

  const size_t baseNeed = (33554432UL + 16777216UL) * 2;
  if (ws_size < baseNeed) return;
  const bool useWh = ws_size >= baseNeed + 49152UL * 2;

  if (useWh) convert_w_kernel<<<48, 256, 0, stream>>>(wq, wh);
  qkv_proj_kernel<<<dim3(256, 8), 256, 0, stream>>>(x, wq, useWh ? wh : nullptr, bq, qk2, vT2);
  attn_kernel<<<512, 256, 0, stream>>>(qk2, vT2, (float*)d_out);
}

// Round 12
// 85.344 us; speedup vs baseline: 1.1248x; 1.0623x over previous
//
#include <hip/hip_runtime.h>
#include <hip/hip_bf16.h>
#include <stdint.h>

// WindowAttention fused pipeline for MI355X (gfx950).
// f32 I/O, fp16 MFMA compute internally (f32 accum).
// B=8, N=16384, C=128, H=16, ws=128, head-dim D=1024 (buggy-reshape semantics).
//
// Workspace layouts (tile-permuted so phase-1 stores are 512B-contiguous):
//  qk2[b][ft 2048][cb 8][tile 256 u16]  tile = [eg 4][cl 16][4 f]   (f = h*1024+d | +16384 for K)
//  vT2[b][h 16][ddt 64][cb 8][tile 256] tile = [cg 4][ddl 16][4 c']
//  wh [384][128] fp16 (optional, after the two buffers)
//
// r12 = r9 qkv (best measured: 55.0us; regular stores keep the workspace
// L2-resident for the consumer — r11 proved nt stores cost attn +26us)
//     + r10 attn (reg-prefetch; ~25us with L2-warm workspace).

#define B_ 8
#define N_ 16384
#define C_ 128
#define H_ 16
#define E3 384
#define DH 1024

typedef float f32x4 __attribute__((ext_vector_type(4)));
typedef _Float16 f16x8 __attribute__((ext_vector_type(8)));
typedef unsigned short u16x8 __attribute__((ext_vector_type(8)));
typedef unsigned short u16x4 __attribute__((ext_vector_type(4)));

#define MFMA16(a, b, c) __builtin_amdgcn_mfma_f32_16x16x32_f16((a), (b), (c), 0, 0, 0)

__device__ __forceinline__ unsigned short f2h(float f) {
  union { _Float16 h; unsigned short u; } x;
  x.h = (_Float16)f;
  return x.u;
}

// ---------------- Phase 0: W f32 -> f16 ---------------------------------
__global__ __launch_bounds__(256) void convert_w_kernel(const float* __restrict__ wq,
                                                        unsigned short* __restrict__ wh) {
  int i = blockIdx.x * 256 + threadIdx.x;  // 12288 threads x 4 elems
  float4 v = ((const float4*)wq)[i];
  u16x4 o;
  o[0] = f2h(v.x); o[1] = f2h(v.y); o[2] = f2h(v.z); o[3] = f2h(v.w);
  ((u16x4*)wh)[i] = o;
}

// ---------------- Phase 1: QKV projection -------------------------------
// Per (b,w): Out[c][e] = sum_d x[b,w*128+d,c] * W[e][d] + bias[e], f = w*384+e.
// esub-split (r9): blockIdx.x = (half<<7) | w; each block stages the full
// x-tile, computes 3 of 6 esub subtiles. Grid 2048 x 8.
__global__ __launch_bounds__(256) void qkv_proj_kernel(
    const float* __restrict__ x,
    const float* __restrict__ wq,
    const unsigned short* __restrict__ wh,   // may be null
    const float* __restrict__ bq,
    unsigned short* __restrict__ qk2,
    unsigned short* __restrict__ vT2) {
  const int w = blockIdx.x & 127;
  const int half = blockIdx.x >> 7;        // esub range: half*3 .. half*3+2
  const int b = blockIdx.y;
  const int t = threadIdx.x;
  const int l = t & 63;
  const int wv = t >> 6;

  __shared__ __align__(16) unsigned short xt[128 * 128];  // swizzled Xt[c][d] (fp16)
  char* xtb = (char*)xt;

  const float* xg = x + ((size_t)(b * N_ + w * 128)) * C_;
  // Transpose-stage: float4 loads (4 consecutive c per lane), packed b128
  // swizzled LDS writes. 512 tasks = 32 c-quads x 16 d-groups.
#pragma unroll
  for (int it = 0; it < 2; ++it) {
    int task = t + it * 256;
    int c0 = (task & 31) * 4;
    int d0 = (task >> 5) * 8;
    u16x8 pk0, pk1, pk2, pk3;
#pragma unroll
    for (int j = 0; j < 8; ++j) {
      float4 v = *(const float4*)(xg + (d0 + j) * C_ + c0);
      pk0[j] = f2h(v.x);
      pk1[j] = f2h(v.y);
      pk2[j] = f2h(v.z);
      pk3[j] = f2h(v.w);
    }
    *(u16x8*)(xtb + c0 * 256 + ((d0 * 2) ^ ((c0 & 7) << 4))) = pk0;
    *(u16x8*)(xtb + (c0 + 1) * 256 + ((d0 * 2) ^ (((c0 + 1) & 7) << 4))) = pk1;
    *(u16x8*)(xtb + (c0 + 2) * 256 + ((d0 * 2) ^ (((c0 + 2) & 7) << 4))) = pk2;
    *(u16x8*)(xtb + (c0 + 3) * 256 + ((d0 * 2) ^ (((c0 + 3) & 7) << 4))) = pk3;
  }
  __syncthreads();

  const int c00 = (wv & 1) * 64;        // wave's c-half
  const int ehalf = (wv >> 1) * 32;     // wave's e-half within 64-wide subtile

  // Hoist X fragments: a(c,d), reused across the block's 3 e-subtiles.
  f16x8 ax[4][4];
#pragma unroll
  for (int mf = 0; mf < 4; ++mf)
#pragma unroll
    for (int ks = 0; ks < 4; ++ks) {
      int cl = c00 + mf * 16 + (l & 15);
      ax[mf][ks] = *(const f16x8*)(xtb + cl * 256 + (((ks * 64) + ((l >> 4) * 16)) ^ ((cl & 7) << 4)));
    }

  const f32x4 fzero = {0.f, 0.f, 0.f, 0.f};
  const bool useWh = (wh != nullptr);

#pragma unroll
  for (int es = 0; es < 3; ++es) {
    const int esub = half * 3 + es;
    const int e00 = esub * 64 + ehalf;
    const int f00 = w * E3 + e00;
    const int type = f00 >> 14;  // 0,1 -> Q/K ; 2 -> V (uniform per 32-wide tile)

    f16x8 bw[2][4];
#pragma unroll
    for (int nf = 0; nf < 2; ++nf)
#pragma unroll
      for (int ks = 0; ks < 4; ++ks) {
        int e = e00 + nf * 16 + (l & 15);
        if (useWh) {
          bw[nf][ks] = *(const f16x8*)(wh + e * 128 + ks * 32 + ((l >> 4) * 8));
        } else {
          const float* wp = wq + e * 128 + ks * 32 + ((l >> 4) * 8);
          float4 w0 = *(const float4*)(wp);
          float4 w1 = *(const float4*)(wp + 4);
          f16x8 bb;
          bb[0] = (_Float16)w0.x; bb[1] = (_Float16)w0.y;
          bb[2] = (_Float16)w0.z; bb[3] = (_Float16)w0.w;
          bb[4] = (_Float16)w1.x; bb[5] = (_Float16)w1.y;
          bb[6] = (_Float16)w1.z; bb[7] = (_Float16)w1.w;
          bw[nf][ks] = bb;
        }
      }

    f32x4 acc[4][2];
#pragma unroll
    for (int mf = 0; mf < 4; ++mf)
#pragma unroll
      for (int nf = 0; nf < 2; ++nf) acc[mf][nf] = fzero;

    if (type < 2) {
      // D[e][c] = mfma(W, X): tile [eg=l>>4][cl=l&15][4 e] -> lane*8B contiguous.
#pragma unroll
      for (int ks = 0; ks < 4; ++ks)
#pragma unroll
        for (int mf = 0; mf < 4; ++mf)
#pragma unroll
          for (int nf = 0; nf < 2; ++nf)
            acc[mf][nf] = MFMA16(bw[nf][ks], ax[mf][ks], acc[mf][nf]);
#pragma unroll
      for (int nf = 0; nf < 2; ++nf) {
        int ft = (f00 + nf * 16) >> 4;
        float4 bb = *(const float4*)(bq + e00 + nf * 16 + ((l >> 4) * 4));
#pragma unroll
        for (int mf = 0; mf < 4; ++mf) {
          int cb = (c00 >> 4) + mf;
          size_t tb = (((size_t)b * 2048 + ft) * 8 + cb) * 256;
          u16x4 ov;
          ov[0] = f2h(acc[mf][nf][0] + bb.x);
          ov[1] = f2h(acc[mf][nf][1] + bb.y);
          ov[2] = f2h(acc[mf][nf][2] + bb.z);
          ov[3] = f2h(acc[mf][nf][3] + bb.w);
          *(u16x4*)(qk2 + tb + l * 4) = ov;
        }
      }
    } else {
      // D[c][e] = mfma(X, W): tile [cg=l>>4][ddl=l&15][4 c] -> lane*8B contiguous.
#pragma unroll
      for (int ks = 0; ks < 4; ++ks)
#pragma unroll
        for (int mf = 0; mf < 4; ++mf)
#pragma unroll
          for (int nf = 0; nf < 2; ++nf)
            acc[mf][nf] = MFMA16(ax[mf][ks], bw[nf][ks], acc[mf][nf]);
#pragma unroll
      for (int nf = 0; nf < 2; ++nf) {
        int fnf = f00 + nf * 16;
        int hh = (fnf >> 10) & 15;
        int ddt = (fnf & 1023) >> 4;
        float bias = bq[e00 + nf * 16 + (l & 15)];  // bias for this lane's e-column
#pragma unroll
        for (int mf = 0; mf < 4; ++mf) {
          int cb = (c00 >> 4) + mf;
          size_t tb = ((((size_t)b * 16 + hh) * 64 + ddt) * 8 + cb) * 256;
          u16x4 ov;
#pragma unroll
          for (int r = 0; r < 4; ++r) ov[r] = f2h(acc[mf][nf][r] + bias);
          *(u16x4*)(vT2 + tb + l * 4) = ov;
        }
      }
    }
  }
}

// ---------------- Phase 2: attention ------------------------------------
// grid 512 = 4 q-quarters (ch = bid>>7) x 128 (b,h) (bh = bid&127).
// T14: Q/K (and V) tiles for the next chunk are reg-prefetched during MFMA.
__global__ __launch_bounds__(256) void attn_kernel(
    const unsigned short* __restrict__ qk2,
    const unsigned short* __restrict__ vT2,
    float* __restrict__ out) {
  const int bid = blockIdx.x;
  const int ch = bid >> 7;               // q-row quarter [0,4)
  const int bh = bid & 127;              // (b,h) [0,128)
  const int b = bh >> 4;
  const int h = bh & 15;
  const int t = threadIdx.x;
  const int l = t & 63;
  const int wv = t >> 6;

  __shared__ __align__(16) char smem[8192 + 32768 + 2048];
  char* QS = smem;                        // Q tiles (32 rows x 256B), later P
  char* KS = smem + 8192;                 // K tiles / V tiles (128 rows x 256B)
  float* RED = (float*)(smem + 40960);    // [32][4] max ; +256 floats: [32][4] sum

  const f32x4 fzero = {0.f, 0.f, 0.f, 0.f};
  f32x4 acc[2][2];
#pragma unroll
  for (int mf = 0; mf < 2; ++mf)
#pragma unroll
    for (int nf = 0; nf < 2; ++nf) acc[mf][nf] = fzero;

  const int e0w = wv * 32;

  // ---- S = Q K^T over d=1024 in 8 chunks of 128, reg-prefetched ----
  uint4 qv[2], kv[8];
  {
    const int ft0q = h * 64;
    const int ft0k = 1024 + h * 64;
#pragma unroll
    for (int i = 0; i < 2; ++i) {
      int idx = t + i * 256;
      int ftl = idx >> 6, cbl = (idx >> 5) & 1, m = idx & 31;
      qv[i] = *(const uint4*)(qk2 + (((size_t)b * 2048 + ft0q + ftl) * 8 + ch * 2 + cbl) * 256 + m * 8);
    }
#pragma unroll
    for (int i = 0; i < 8; ++i) {
      int idx = t + i * 256;
      int ftl = idx >> 8, cb = (idx >> 5) & 7, m = idx & 31;
      kv[i] = *(const uint4*)(qk2 + (((size_t)b * 2048 + ft0k + ftl) * 8 + cb) * 256 + m * 8);
    }
  }

  for (int dc = 0; dc < 8; ++dc) {
    if (dc) __syncthreads();  // prev MFMA done reading LDS
    // LDS writes from staged regs
#pragma unroll
    for (int i = 0; i < 2; ++i) {
      int idx = t + i * 256;
      int ftl = idx >> 6, cbl = (idx >> 5) & 1, m = idx & 31;
      int row0 = cbl * 16 + (m & 7) * 2;
      int fb = ftl * 32 + (m >> 3) * 8;
      uint4 v = qv[i];
      *(uint2*)(QS + row0 * 256 + (fb ^ ((row0 & 7) << 4))) = make_uint2(v.x, v.y);
      *(uint2*)(QS + (row0 + 1) * 256 + (fb ^ (((row0 + 1) & 7) << 4))) = make_uint2(v.z, v.w);
    }
#pragma unroll
    for (int i = 0; i < 8; ++i) {
      int idx = t + i * 256;
      int ftl = idx >> 8, cb = (idx >> 5) & 7, m = idx & 31;
      int row0 = cb * 16 + (m & 7) * 2;
      int fb = ftl * 32 + (m >> 3) * 8;
      uint4 v = kv[i];
      *(uint2*)(KS + row0 * 256 + (fb ^ ((row0 & 7) << 4))) = make_uint2(v.x, v.y);
      *(uint2*)(KS + (row0 + 1) * 256 + (fb ^ (((row0 + 1) & 7) << 4))) = make_uint2(v.z, v.w);
    }
    __syncthreads();  // tiles visible

    if (dc < 7) {  // prefetch next chunk; lands during MFMA below
      const int ft0q = h * 64 + (dc + 1) * 8;
      const int ft0k = 1024 + h * 64 + (dc + 1) * 8;
#pragma unroll
      for (int i = 0; i < 2; ++i) {
        int idx = t + i * 256;
        int ftl = idx >> 6, cbl = (idx >> 5) & 1, m = idx & 31;
        qv[i] = *(const uint4*)(qk2 + (((size_t)b * 2048 + ft0q + ftl) * 8 + ch * 2 + cbl) * 256 + m * 8);
      }
#pragma unroll
      for (int i = 0; i < 8; ++i) {
        int idx = t + i * 256;
        int ftl = idx >> 8, cb = (idx >> 5) & 7, m = idx & 31;
        kv[i] = *(const uint4*)(qk2 + (((size_t)b * 2048 + ft0k + ftl) * 8 + cb) * 256 + m * 8);
      }
    }

#pragma unroll
    for (int ks = 0; ks < 4; ++ks) {
      f16x8 aQ[2], bK[2];
#pragma unroll
      for (int mf = 0; mf < 2; ++mf) {
        int cl = mf * 16 + (l & 15);
        aQ[mf] = *(const f16x8*)(QS + cl * 256 + (((ks * 64) + ((l >> 4) * 16)) ^ ((cl & 7) << 4)));
      }
#pragma unroll
      for (int nf = 0; nf < 2; ++nf) {
        int el = e0w + nf * 16 + (l & 15);
        bK[nf] = *(const f16x8*)(KS + el * 256 + (((ks * 64) + ((l >> 4) * 16)) ^ ((el & 7) << 4)));
      }
#pragma unroll
      for (int mf = 0; mf < 2; ++mf)
#pragma unroll
        for (int nf = 0; nf < 2; ++nf)
          acc[mf][nf] = MFMA16(aQ[mf], bK[nf], acc[mf][nf]);  // D[c][e]
    }
  }

  // ---- V(dc2=0) prefetch: hides under softmax ----
  uint4 vv[8];
#pragma unroll
  for (int i = 0; i < 8; ++i) {
    int idx = t + i * 256;
    int ddtl = idx >> 8, cb = (idx >> 5) & 7, m = idx & 31;
    vv[i] = *(const uint4*)(vT2 + ((((size_t)(b * 16 + h)) * 64 + ddtl) * 8 + cb) * 256 + m * 8);
  }

  // ---- softmax over e (rows c rel), cross-wave combine via RED ----
  const float SC = 0.35355339059327f * 1.44269504088896f;  // 8^-0.5 * log2(e)
  float mrow[2][4];
#pragma unroll
  for (int mf = 0; mf < 2; ++mf)
#pragma unroll
    for (int r = 0; r < 4; ++r) {
      float mx = fmaxf(acc[mf][0][r], acc[mf][1][r]);
      mx = fmaxf(mx, __shfl_xor(mx, 1));
      mx = fmaxf(mx, __shfl_xor(mx, 2));
      mx = fmaxf(mx, __shfl_xor(mx, 4));
      mx = fmaxf(mx, __shfl_xor(mx, 8));
      int cl = mf * 16 + ((l >> 4) * 4) + r;
      if ((l & 15) == 0) RED[cl * 4 + wv] = mx;
    }
  __syncthreads();
#pragma unroll
  for (int mf = 0; mf < 2; ++mf)
#pragma unroll
    for (int r = 0; r < 4; ++r) {
      int cl = mf * 16 + ((l >> 4) * 4) + r;
      float4 v = *(const float4*)(RED + cl * 4);
      mrow[mf][r] = fmaxf(fmaxf(v.x, v.y), fmaxf(v.z, v.w));
    }
#pragma unroll
  for (int mf = 0; mf < 2; ++mf)
#pragma unroll
    for (int r = 0; r < 4; ++r) {
      float s0 = 0.f;
#pragma unroll
      for (int nf = 0; nf < 2; ++nf) {
        float p = exp2f((acc[mf][nf][r] - mrow[mf][r]) * SC);
        acc[mf][nf][r] = p;
        s0 += p;
      }
      s0 += __shfl_xor(s0, 1);
      s0 += __shfl_xor(s0, 2);
      s0 += __shfl_xor(s0, 4);
      s0 += __shfl_xor(s0, 8);
      int cl = mf * 16 + ((l >> 4) * 4) + r;
      if ((l & 15) == 0) RED[256 + cl * 4 + wv] = s0;
    }
  // write P (fp16) into QS
#pragma unroll
  for (int mf = 0; mf < 2; ++mf)
#pragma unroll
    for (int nf = 0; nf < 2; ++nf)
#pragma unroll
      for (int r = 0; r < 4; ++r) {
        int cl = mf * 16 + ((l >> 4) * 4) + r;
        int el = e0w + nf * 16 + (l & 15);
        *(unsigned short*)(QS + cl * 256 + ((el * 2) ^ ((cl & 7) << 4))) = f2h(acc[mf][nf][r]);
      }
  __syncthreads();
  float invc[2];
#pragma unroll
  for (int mf = 0; mf < 2; ++mf) {
    int cl = mf * 16 + (l & 15);
    float4 v = *(const float4*)(RED + 256 + cl * 4);
    invc[mf] = 1.f / (v.x + v.y + v.z + v.w);
  }

  // ---- O = P V; D[d][c] via mfma(V,P); V tiles reg-prefetched ----
  for (int dc2 = 0; dc2 < 8; ++dc2) {
    if (dc2) __syncthreads();  // prev MFMA done reading KS
    // write KS (V^T chunk) from staged regs
#pragma unroll
    for (int i = 0; i < 8; ++i) {
      int idx = t + i * 256;
      int ddtl = idx >> 8, cb = (idx >> 5) & 7, m = idx & 31;
      int row0 = ddtl * 16 + (m & 7) * 2;
      int cbyte = cb * 32 + (m >> 3) * 8;
      uint4 v = vv[i];
      *(uint2*)(KS + row0 * 256 + (cbyte ^ ((row0 & 7) << 4))) = make_uint2(v.x, v.y);
      *(uint2*)(KS + (row0 + 1) * 256 + (cbyte ^ (((row0 + 1) & 7) << 4))) = make_uint2(v.z, v.w);
    }
    __syncthreads();

    if (dc2 < 7) {  // prefetch next V chunk
#pragma unroll
      for (int i = 0; i < 8; ++i) {
        int idx = t + i * 256;
        int ddtl = idx >> 8, cb = (idx >> 5) & 7, m = idx & 31;
        vv[i] = *(const uint4*)(vT2 + ((((size_t)(b * 16 + h)) * 64 + (dc2 + 1) * 8 + ddtl) * 8 + cb) * 256 + m * 8);
      }
    }

    f32x4 acc2[2][2];  // [nf: d-tile][mf: c-tile]
#pragma unroll
    for (int nf = 0; nf < 2; ++nf)
#pragma unroll
      for (int mf = 0; mf < 2; ++mf) acc2[nf][mf] = fzero;

#pragma unroll
    for (int ks = 0; ks < 4; ++ks) {
      f16x8 aP[2], bV[2];
#pragma unroll
      for (int mf = 0; mf < 2; ++mf) {
        int cl = mf * 16 + (l & 15);
        aP[mf] = *(const f16x8*)(QS + cl * 256 + (((ks * 64) + ((l >> 4) * 16)) ^ ((cl & 7) << 4)));
      }
#pragma unroll
      for (int nf = 0; nf < 2; ++nf) {
        int dl = e0w + nf * 16 + (l & 15);
        bV[nf] = *(const f16x8*)(KS + dl * 256 + (((ks * 64) + ((l >> 4) * 16)) ^ ((dl & 7) << 4)));
      }
#pragma unroll
      for (int nf = 0; nf < 2; ++nf)
#pragma unroll
        for (int mf = 0; mf < 2; ++mf)
          acc2[nf][mf] = MFMA16(bV[nf], aP[mf], acc2[nf][mf]);  // D[d][c]
    }

#pragma unroll
    for (int nf = 0; nf < 2; ++nf)
#pragma unroll
      for (int mf = 0; mf < 2; ++mf) {
        int c = ch * 32 + mf * 16 + (l & 15);
#pragma unroll
        for (int r = 0; r < 4; ++r) {
          int d = dc2 * 128 + e0w + nf * 16 + ((l >> 4) * 4) + r;
          out[((size_t)(b * N_ + h * DH + d)) * C_ + c] = acc2[nf][mf][r] * invc[mf];
        }
      }
  }
}

extern "C" void kernel_launch(void* const* d_in, const int* in_sizes, int n_in,
                              void* d_out, int out_size, void* d_ws, size_t ws_size,
                              hipStream_t stream) {
  const float* x = (const float*)d_in[0];
  const float* wq = (const float*)d_in[1];
  const float* bq = (const float*)d_in[2];
  unsigned short* qk2 = (unsigned short*)d_ws;              // 33,554,432 u16
  unsigned short* vT2 = qk2 + 33554432UL;                   // 16,777,216 u16
  unsigned short* wh = vT2 + 16777216UL;                    // 49,152 u16 (optional)

  const size_t baseNeed = (33554432UL + 16777216UL) * 2;
  if (ws_size < baseNeed) return;
  const bool useWh = ws_size >= baseNeed + 49152UL * 2;

  if (useWh) convert_w_kernel<<<48, 256, 0, stream>>>(wq, wh);
  qkv_proj_kernel<<<dim3(256, 8), 256, 0, stream>>>(x, wq, useWh ? wh : nullptr, bq, qk2, vT2);
  attn_kernel<<<512, 256, 0, stream>>>(qk2, vT2, (float*)d_out);
}